// Round 24
// baseline (136.156 us; speedup 1.0000x reference)
//
#include <hip/hip_runtime.h>
#include <stdint.h>

#define LOG2G -0.045803689611862786f   // log2(0.96875)

typedef float f32x4 __attribute__((ext_vector_type(4)));
typedef short bf16x8 __attribute__((ext_vector_type(8)));

__device__ inline unsigned short f2bf(float f) {
  uint32_t u = __builtin_bit_cast(uint32_t, f);
  u += 0x7FFFu + ((u >> 16) & 1u);     // RNE
  return (unsigned short)(u >> 16);
}
__device__ inline float b2f(unsigned short u) {
  return __builtin_bit_cast(float, (uint32_t)u << 16);
}

#if __has_builtin(__builtin_amdgcn_global_load_lds)
#define USE_GLL 1
#endif

// Stage one 1KB row (512 bf16) of global into LDS. Lane l covers granule l (16B).
__device__ __forceinline__ void stage_row(const unsigned short* __restrict__ srcrow,
                                          unsigned short* ldsrow, int lane, int swz) {
#ifdef USE_GLL
  __builtin_amdgcn_global_load_lds(
      (const __attribute__((address_space(1))) uint32_t*)((const char*)srcrow + ((lane ^ swz) << 4)),
      (__attribute__((address_space(3))) uint32_t*)ldsrow, 16, 0, 0);
#else
  bf16x8 v = *(const bf16x8*)((const char*)srcrow + ((lane ^ swz) << 4));
  *(bf16x8*)((char*)ldsrow + (lane << 4)) = v;
#endif
}

// ---------------- Stage 0a: transpose W -> Wt[n][k] bf16 ----------------
__global__ __launch_bounds__(256) void prep_kernel(
    const float* __restrict__ wq, const float* __restrict__ wk,
    const float* __restrict__ wv, unsigned short* __restrict__ Wt)
{
  __shared__ unsigned short lh[64][68];
  const int blk = blockIdx.x;
  const int w3 = blk >> 6;
  const int tile = blk & 63;
  const int tk = (tile >> 3) * 64, tn = (tile & 7) * 64;
  const float* W = (w3 == 0) ? wq : ((w3 == 1) ? wk : wv);
  const int t = threadIdx.x;
  {
    const int kl = t >> 2, nq = (t & 3) * 16;
#pragma unroll
    for (int f = 0; f < 4; ++f) {
      float4 v = *(const float4*)&W[(size_t)(tk + kl) * 512 + tn + nq + f * 4];
      float vv[4] = {v.x, v.y, v.z, v.w};
      ushort4 h4;
#pragma unroll
      for (int e = 0; e < 4; ++e) ((unsigned short*)&h4)[e] = f2bf(vv[e]);
      *(ushort4*)&lh[kl][nq + f * 4] = h4;
    }
  }
  __syncthreads();
  {
    const int nl = t >> 2, kq = (t & 3) * 16;
    unsigned short* outh = Wt + (size_t)w3 * 262144 + (size_t)(tn + nl) * 512 + tk + kq;
#pragma unroll
    for (int f = 0; f < 4; ++f) {
      ushort4 h4;
#pragma unroll
      for (int e = 0; e < 4; ++e) ((unsigned short*)&h4)[e] = lh[kq + f * 4 + e][nl];
      *(ushort4*)&outh[f * 4] = h4;
    }
  }
}

// ---------------- Stage 0b: x fp32 -> bf16 ----------------
__global__ __launch_bounds__(256) void xconv_kernel(
    const float* __restrict__ x, unsigned short* __restrict__ xb)
{
  const size_t i = ((size_t)blockIdx.x * 256 + threadIdx.x) * 8;
  float4 v0 = *(const float4*)&x[i];
  float4 v1 = *(const float4*)&x[i + 4];
  bf16x8 o;
  o[0] = (short)f2bf(v0.x); o[1] = (short)f2bf(v0.y);
  o[2] = (short)f2bf(v0.z); o[3] = (short)f2bf(v0.w);
  o[4] = (short)f2bf(v1.x); o[5] = (short)f2bf(v1.y);
  o[6] = (short)f2bf(v1.z); o[7] = (short)f2bf(v1.w);
  *(bf16x8*)&xb[i] = o;
}

// ---------------- Stage 1: proj, 128m x 64n, A-in-regs, 2 blocks/CU ----------------
// r23 structure with Ts dropped: single T buffer, Q/K epilogue in 2 passes
// (cos fill/store, barrier, sin fill/store). LDS 80 KB -> 2 blocks co-resident;
// one block's staging drains hide under the other's compute. VGPR ~116 < 128 budget.
__global__ __launch_bounds__(512, 4) void proj_kernel(
    const unsigned short* __restrict__ xb, const unsigned short* __restrict__ Wt,
    const float* __restrict__ theta,
    unsigned short* __restrict__ Qc, unsigned short* __restrict__ Qs,
    unsigned short* __restrict__ Kc, unsigned short* __restrict__ Ks,
    unsigned short* __restrict__ Vt)
{
  __shared__ unsigned short Bl[64 * 512];   // 64 KB  W plane (swizzled granules)
  __shared__ unsigned short T[128 * 64];    // 16 KB  (one plane at a time; V as [64][128])
  const int tid = threadIdx.x;
  const int wave = tid >> 6, lane = tid & 63;
  const int r = lane & 15, g = lane >> 4;
  const int nbase = blockIdx.x * 64, mbase = blockIdx.y * 128;
  const int b = mbase >> 11, posb = mbase & 2047;

  // ---- A-frags: wave's 16 m-rows x 512 k in registers (ret-Q pattern) ----
  bf16x8 aa[16];
  {
    const unsigned short* ar = xb + (size_t)(mbase + wave * 16 + r) * 512 + g * 8;
#pragma unroll
    for (int ks = 0; ks < 16; ++ks) aa[ks] = *(const bf16x8*)(ar + ks * 32);
  }
#pragma unroll
  for (int ks = 0; ks < 16; ++ks)
    asm volatile("" : "+v"(aa[ks]));       // pin: forbid remat from global

  // ---- stage W plane 0 ----
#pragma unroll
  for (int i = 0; i < 8; ++i) {
    const int row = wave * 8 + i;
    stage_row(Wt + (size_t)(nbase + row) * 512, &Bl[row * 512], lane, row & 7);
  }

  // ---- rotation constants for 4 n-frags ----
  float C1[4], S1[4], CZ[4], SZ[4];
  const int pos0 = posb + wave * 16 + g * 4;
#pragma unroll
  for (int nf = 0; nf < 4; ++nf) {
    const float th = theta[nbase + nf * 16 + r];
    float c1, s1, cz, sz;
    sincosf(th, &s1, &c1);
    sincosf((float)(pos0 + 1) * th, &sz, &cz);
    C1[nf] = c1; S1[nf] = s1; CZ[nf] = cz; SZ[nf] = sz;
  }
  __syncthreads();   // staging visible (own-wave vmcnt drained at barrier)

#pragma unroll
  for (int z = 0; z < 3; ++z) {
    // ---- compute: wave -> 16m x 64n (4 n-frag chains) ----
    f32x4 acc[4];
#pragma unroll
    for (int nf = 0; nf < 4; ++nf) acc[nf] = (f32x4){0.f, 0.f, 0.f, 0.f};
#pragma unroll
    for (int ks = 0; ks < 16; ++ks) {
      const int off = (((ks * 4) + g) ^ (r & 7)) << 3;
#pragma unroll
      for (int nf = 0; nf < 4; ++nf) {
        bf16x8 bb = *(const bf16x8*)&Bl[(nf * 16 + r) * 512 + off];
        acc[nf] = __builtin_amdgcn_mfma_f32_16x16x32_bf16(aa[ks], bb, acc[nf], 0, 0, 0);
      }
    }
    __syncthreads();   // all waves done reading Bl

    // ---- issue staging of next W plane into Bl (drains at epilogue barrier) ----
    if (z < 2) {
#pragma unroll
      for (int i = 0; i < 8; ++i) {
        const int row = wave * 8 + i;
        stage_row(Wt + (size_t)(z + 1) * 262144 + (size_t)(nbase + row) * 512,
                  &Bl[row * 512], lane, row & 7);
      }
    }

    // ---- epilogue ----
    if (z == 2) {
      // V: T as [n 64][pos 128], 16-granule XOR swizzle
#pragma unroll
      for (int nf = 0; nf < 4; ++nf) {
        const int nl = nf * 16 + r;
#pragma unroll
        for (int i = 0; i < 4; ++i) {
          const int pos = wave * 16 + g * 4 + i;
          const int sg = (pos >> 3) ^ (nl & 7);
          T[nl * 128 + sg * 8 + (pos & 7)] = f2bf(acc[nf][i]);
        }
      }
      __syncthreads();
#pragma unroll
      for (int pass = 0; pass < 2; ++pass) {
        const int row = tid >> 3;                 // 0..63 (n_local)
        const int gg = pass * 8 + (tid & 7);      // 0..15 (pos granule)
        const int sg = gg ^ (row & 7);
        bf16x8 v = *(const bf16x8*)&T[row * 128 + sg * 8];
        *(bf16x8*)&Vt[((size_t)b * 512 + nbase + row) * 2048 + posb + gg * 8] = v;
      }
    } else {
      // Q/K: two passes through one T buffer (cos plane, then sin plane)
#pragma unroll
      for (int pl = 0; pl < 2; ++pl) {
        if (pl) __syncthreads();           // prior plane's T reads complete
#pragma unroll
        for (int nf = 0; nf < 4; ++nf) {
          const int nl = nf * 16 + r;
          float cc = CZ[nf], ss = SZ[nf];
          const float c1 = C1[nf], s1 = S1[nf];
#pragma unroll
          for (int i = 0; i < 4; ++i) {
            const int mrow = wave * 16 + g * 4 + i;
            const int sc = ((((nl >> 3) ^ (mrow & 7)) << 3) | (nl & 7));
            T[mrow * 64 + sc] = f2bf(acc[nf][i] * (pl ? ss : cc));
            float nc = cc * c1 - ss * s1, ns = cc * s1 + ss * c1;
            cc = nc; ss = ns;
          }
        }
        __syncthreads();                    // fill done (pass 0 also drains W staging)
        unsigned short* dst = (z == 0) ? (pl ? Qs : Qc) : (pl ? Ks : Kc);
#pragma unroll
        for (int pass = 0; pass < 2; ++pass) {
          const int row = pass * 64 + (tid >> 3);   // 0..127 (m_local)
          const int lg = tid & 7;
          const int sc8 = (lg ^ (row & 7)) << 3;
          bf16x8 v = *(const bf16x8*)&T[row * 64 + sc8];
          *(bf16x8*)&dst[(size_t)(mbase + row) * 512 + nbase + lg * 8] = v;
        }
      }
    }
    __syncthreads();                        // T reads + staging complete before next z
  }
}

// ---------------- Stage 2: retention, QBLK=32 via q-group waves, m-tile 32 ----------
// (verbatim r18/r23 — proven) Output pack (verified): im | re<<16.
__global__ __launch_bounds__(256, 1) void ret_kernel(
    const unsigned short* __restrict__ Qc, const unsigned short* __restrict__ Qs,
    const unsigned short* __restrict__ Kc, const unsigned short* __restrict__ Ks,
    const unsigned short* __restrict__ Vt, uint32_t* __restrict__ out)
{
  __shared__ unsigned short Klds[64 * 512];   // rows 0-31: Kc, 32-63: Ks (swz granules)
  __shared__ unsigned short Prl[2][16 * 40];
  __shared__ unsigned short Pil[2][16 * 40];

  const int bid = blockIdx.x;
  const int sid = ((bid & 7) << 5) + (bid >> 3);  // XCD chunk swizzle (bijective, 256=8*32)
  const int b = sid >> 6;
  const int qblk = 63 - (sid & 63);               // heavy-first
  const int q0 = qblk * 32;
  const int tid = threadIdx.x;
  const int wave = tid >> 6;
  const int lane = tid & 63;
  const int r = lane & 15;
  const int g = lane >> 4;
  const int mf = wave & 1;
  const int wq = wave >> 1;
  const int sw = r & 7;

  bf16x8 qa[16], qb[16];
  {
    const unsigned short* qcr = Qc + ((size_t)b * 2048 + q0 + wq * 16 + r) * 512 + g * 8;
    const unsigned short* qsr = Qs + ((size_t)b * 2048 + q0 + wq * 16 + r) * 512 + g * 8;
#pragma unroll
    for (int ks = 0; ks < 16; ++ks) {
      qa[ks] = *(const bf16x8*)(qcr + ks * 32);
      qb[ks] = *(const bf16x8*)(qsr + ks * 32);
    }
  }
#pragma unroll
  for (int ks = 0; ks < 16; ++ks)
    asm volatile("" : "+v"(qa[ks]), "+v"(qb[ks]));   // pin: forbid remat from global

  const int ntiles = ((q0 + 31) >> 5) + 1;
  const int t0 = (q0 >= 256) ? ((q0 - 256) >> 5) : 0;   // decay band start (32-grain)

  {
    const size_t kbase = ((size_t)b * 2048 + (t0 << 5)) * 512;
#pragma unroll
    for (int i = 0; i < 16; ++i) {
      const int rid = wave * 16 + i;
      const int row = rid & 31;
      const unsigned short* src = ((rid < 32) ? Kc : Ks) + kbase + (size_t)row * 512;
      stage_row(src, &Klds[(size_t)rid * 512], lane, rid & 7);
    }
  }
  __syncthreads();

  f32x4 outre[2][8], outim[2][8];
#pragma unroll
  for (int qg = 0; qg < 2; ++qg)
#pragma unroll
    for (int c = 0; c < 8; ++c) {
      outre[qg][c] = (f32x4){0.f, 0.f, 0.f, 0.f};
      outim[qg][c] = (f32x4){0.f, 0.f, 0.f, 0.f};
    }

  for (int t = t0; t < ntiles; ++t) {
    const int m0 = t << 5;
    f32x4 acc_cc = {0.f, 0.f, 0.f, 0.f};
    f32x4 acc_ss = {0.f, 0.f, 0.f, 0.f};
    f32x4 ai1 = {0.f, 0.f, 0.f, 0.f};
    f32x4 ai2 = {0.f, 0.f, 0.f, 0.f};
    const unsigned short* krow_c = &Klds[(mf * 16 + r) * 512];
    const unsigned short* krow_s = krow_c + 32 * 512;
#pragma unroll
    for (int ks = 0; ks < 16; ++ks) {
      const int off = (((ks * 4) + g) ^ sw) << 3;
      bf16x8 ka = *(const bf16x8*)(krow_c + off);
      bf16x8 kb = *(const bf16x8*)(krow_s + off);
      acc_cc = __builtin_amdgcn_mfma_f32_16x16x32_bf16(ka, qa[ks], acc_cc, 0, 0, 0);
      acc_ss = __builtin_amdgcn_mfma_f32_16x16x32_bf16(kb, qb[ks], acc_ss, 0, 0, 0);
      ai1    = __builtin_amdgcn_mfma_f32_16x16x32_bf16(ka, qb[ks], ai1, 0, 0, 0);
      ai2    = __builtin_amdgcn_mfma_f32_16x16x32_bf16(kb, qa[ks], ai2, 0, 0, 0);
    }
    {
      const int qrow = q0 + wq * 16 + r;
      const int mg = m0 + mf * 16 + g * 4;
      ushort4 pkre, pkim;
#pragma unroll
      for (int rg = 0; rg < 4; ++rg) {
        int d = qrow - (mg + rg);
        float wdec = (d >= 0) ? exp2f((float)d * LOG2G) : 0.0f;
        ((unsigned short*)&pkre)[rg] = f2bf((acc_cc[rg] + acc_ss[rg]) * wdec);
        ((unsigned short*)&pkim)[rg] = f2bf((ai1[rg] - ai2[rg]) * wdec);
      }
      *(ushort4*)&Prl[wq][r * 40 + mf * 16 + g * 4] = pkre;
      *(ushort4*)&Pil[wq][r * 40 + mf * 16 + g * 4] = pkim;
    }
    __syncthreads();

    const unsigned short* vtp =
        Vt + ((size_t)b * 512 + wave * 128 + r) * 2048 + m0 + g * 8;
    bf16x8 vv[8];
#pragma unroll
    for (int c = 0; c < 8; ++c)
      vv[c] = *(const bf16x8*)(vtp + (size_t)c * 16 * 2048);

    if (t + 1 < ntiles) {
      const size_t kbase = ((size_t)b * 2048 + m0 + 32) * 512;
#pragma unroll
      for (int i = 0; i < 16; ++i) {
        const int rid = wave * 16 + i;
        const int row = rid & 31;
        const unsigned short* src = ((rid < 32) ? Kc : Ks) + kbase + (size_t)row * 512;
        stage_row(src, &Klds[(size_t)rid * 512], lane, rid & 7);
      }
    }

#pragma unroll
    for (int qg = 0; qg < 2; ++qg) {
      bf16x8 pr = *(const bf16x8*)&Prl[qg][r * 40 + g * 8];
      bf16x8 pi = *(const bf16x8*)&Pil[qg][r * 40 + g * 8];
#pragma unroll
      for (int c = 0; c < 8; ++c) {
        outre[qg][c] = __builtin_amdgcn_mfma_f32_16x16x32_bf16(pr, vv[c], outre[qg][c], 0, 0, 0);
        outim[qg][c] = __builtin_amdgcn_mfma_f32_16x16x32_bf16(pi, vv[c], outim[qg][c], 0, 0, 0);
      }
    }
    __syncthreads();
  }

#pragma unroll
  for (int qg = 0; qg < 2; ++qg)
#pragma unroll
    for (int c = 0; c < 8; ++c)
#pragma unroll
      for (int rg = 0; rg < 4; ++rg) {
        const int q = q0 + qg * 16 + g * 4 + rg;
        const int h = wave * 128 + c * 16 + r;
        const size_t o = ((size_t)b * 2048 + q) * 512 + h;
        out[o] = (uint32_t)f2bf(outim[qg][c][rg]) | ((uint32_t)f2bf(outre[qg][c][rg]) << 16);
      }
}

extern "C" void kernel_launch(void* const* d_in, const int* in_sizes, int n_in,
                              void* d_out, int out_size, void* d_ws, size_t ws_size,
                              hipStream_t stream) {
  (void)in_sizes; (void)n_in; (void)out_size; (void)ws_size;
  const float* x     = (const float*)d_in[0];
  const float* wq    = (const float*)d_in[1];
  const float* wk    = (const float*)d_in[2];
  const float* wv    = (const float*)d_in[3];
  const float* theta = (const float*)d_in[4];

  const size_t NEL = (size_t)4 * 2048 * 512;   // elements per bf16 matrix
  unsigned short* Qc = (unsigned short*)d_ws;
  unsigned short* Qs = Qc + NEL;
  unsigned short* Kc = Qs + NEL;
  unsigned short* Ks = Kc + NEL;
  unsigned short* Vt = Ks + NEL;               // [B][H][S]
  // transient buffers in d_out (fully overwritten by ret_kernel afterwards)
  unsigned short* Wt = (unsigned short*)d_out;             // 1.5 MB
  unsigned short* xb = (unsigned short*)d_out + 2097152;   // 8.4 MB @ 4MB offset

  prep_kernel<<<192, 256, 0, stream>>>(wq, wk, wv, Wt);
  xconv_kernel<<<2048, 256, 0, stream>>>(x, xb);
  dim3 gp(8, 64);
  proj_kernel<<<gp, 512, 0, stream>>>(xb, Wt, theta, Qc, Qs, Kc, Ks, Vt);
  ret_kernel<<<256, 256, 0, stream>>>(Qc, Qs, Kc, Ks, Vt, (uint32_t*)d_out);
}

// Round 25
// 87.376 us; speedup vs baseline: 1.5583x; 1.5583x over previous
//
#include <hip/hip_runtime.h>
#include <stdint.h>

#define LOG2G -0.045803689611862786f   // log2(0.96875)

typedef float f32x4 __attribute__((ext_vector_type(4)));
typedef short bf16x8 __attribute__((ext_vector_type(8)));

__device__ inline unsigned short f2bf(float f) {
  uint32_t u = __builtin_bit_cast(uint32_t, f);
  u += 0x7FFFu + ((u >> 16) & 1u);     // RNE
  return (unsigned short)(u >> 16);
}
__device__ inline float b2f(unsigned short u) {
  return __builtin_bit_cast(float, (uint32_t)u << 16);
}

#if __has_builtin(__builtin_amdgcn_global_load_lds)
#define USE_GLL 1
#endif

// Stage one 1KB row (512 bf16) of global into LDS. Lane l covers granule l (16B).
__device__ __forceinline__ void stage_row(const unsigned short* __restrict__ srcrow,
                                          unsigned short* ldsrow, int lane, int swz) {
#ifdef USE_GLL
  __builtin_amdgcn_global_load_lds(
      (const __attribute__((address_space(1))) uint32_t*)((const char*)srcrow + ((lane ^ swz) << 4)),
      (__attribute__((address_space(3))) uint32_t*)ldsrow, 16, 0, 0);
#else
  bf16x8 v = *(const bf16x8*)((const char*)srcrow + ((lane ^ swz) << 4));
  *(bf16x8*)((char*)ldsrow + (lane << 4)) = v;
#endif
}

// ---------------- Stage 0a: transpose W -> Wt[n][k] bf16 ----------------
__global__ __launch_bounds__(256) void prep_kernel(
    const float* __restrict__ wq, const float* __restrict__ wk,
    const float* __restrict__ wv, unsigned short* __restrict__ Wt)
{
  __shared__ unsigned short lh[64][68];
  const int blk = blockIdx.x;
  const int w3 = blk >> 6;
  const int tile = blk & 63;
  const int tk = (tile >> 3) * 64, tn = (tile & 7) * 64;
  const float* W = (w3 == 0) ? wq : ((w3 == 1) ? wk : wv);
  const int t = threadIdx.x;
  {
    const int kl = t >> 2, nq = (t & 3) * 16;
#pragma unroll
    for (int f = 0; f < 4; ++f) {
      float4 v = *(const float4*)&W[(size_t)(tk + kl) * 512 + tn + nq + f * 4];
      float vv[4] = {v.x, v.y, v.z, v.w};
      ushort4 h4;
#pragma unroll
      for (int e = 0; e < 4; ++e) ((unsigned short*)&h4)[e] = f2bf(vv[e]);
      *(ushort4*)&lh[kl][nq + f * 4] = h4;
    }
  }
  __syncthreads();
  {
    const int nl = t >> 2, kq = (t & 3) * 16;
    unsigned short* outh = Wt + (size_t)w3 * 262144 + (size_t)(tn + nl) * 512 + tk + kq;
#pragma unroll
    for (int f = 0; f < 4; ++f) {
      ushort4 h4;
#pragma unroll
      for (int e = 0; e < 4; ++e) ((unsigned short*)&h4)[e] = lh[kq + f * 4 + e][nl];
      *(ushort4*)&outh[f * 4] = h4;
    }
  }
}

// ---------------- Stage 0b: x fp32 -> bf16 ----------------
__global__ __launch_bounds__(256) void xconv_kernel(
    const float* __restrict__ x, unsigned short* __restrict__ xb)
{
  const size_t i = ((size_t)blockIdx.x * 256 + threadIdx.x) * 8;
  float4 v0 = *(const float4*)&x[i];
  float4 v1 = *(const float4*)&x[i + 4];
  bf16x8 o;
  o[0] = (short)f2bf(v0.x); o[1] = (short)f2bf(v0.y);
  o[2] = (short)f2bf(v0.z); o[3] = (short)f2bf(v0.w);
  o[4] = (short)f2bf(v1.x); o[5] = (short)f2bf(v1.y);
  o[6] = (short)f2bf(v1.z); o[7] = (short)f2bf(v1.w);
  *(bf16x8*)&xb[i] = o;
}

// ---------------- Stage 1: proj, 128m x 64n, A-in-registers, W streamed ----------
// (verbatim r23 — proven 87.7us total) 512 threads / 8 waves; wave owns 16 m-rows
// (A = 16 bf16x8 frags in VGPRs, pinned, 1 wave/SIMD full reg budget — REQUIRED).
// W plane (64 KB) single-buffered; grid (8,64) = 512 blocks = 2 rounds.
__global__ __launch_bounds__(512, 1) void proj_kernel(
    const unsigned short* __restrict__ xb, const unsigned short* __restrict__ Wt,
    const float* __restrict__ theta,
    unsigned short* __restrict__ Qc, unsigned short* __restrict__ Qs,
    unsigned short* __restrict__ Kc, unsigned short* __restrict__ Ks,
    unsigned short* __restrict__ Vt)
{
  __shared__ unsigned short Bl[64 * 512];   // 64 KB  W plane (swizzled granules)
  __shared__ unsigned short Tc[128 * 64];   // 16 KB  (Q/K cos plane, or V as [64][128])
  __shared__ unsigned short Ts[128 * 64];   // 16 KB  (Q/K sin plane)
  const int tid = threadIdx.x;
  const int wave = tid >> 6, lane = tid & 63;
  const int r = lane & 15, g = lane >> 4;
  const int nbase = blockIdx.x * 64, mbase = blockIdx.y * 128;
  const int b = mbase >> 11, posb = mbase & 2047;

  // ---- A-frags: wave's 16 m-rows x 512 k in registers (ret-Q pattern) ----
  bf16x8 aa[16];
  {
    const unsigned short* ar = xb + (size_t)(mbase + wave * 16 + r) * 512 + g * 8;
#pragma unroll
    for (int ks = 0; ks < 16; ++ks) aa[ks] = *(const bf16x8*)(ar + ks * 32);
  }
#pragma unroll
  for (int ks = 0; ks < 16; ++ks)
    asm volatile("" : "+v"(aa[ks]));       // pin: forbid remat from global

  // ---- stage W plane 0 ----
#pragma unroll
  for (int i = 0; i < 8; ++i) {
    const int row = wave * 8 + i;
    stage_row(Wt + (size_t)(nbase + row) * 512, &Bl[row * 512], lane, row & 7);
  }

  // ---- rotation constants for 4 n-frags ----
  float C1[4], S1[4], CZ[4], SZ[4];
  const int pos0 = posb + wave * 16 + g * 4;
#pragma unroll
  for (int nf = 0; nf < 4; ++nf) {
    const float th = theta[nbase + nf * 16 + r];
    float c1, s1, cz, sz;
    sincosf(th, &s1, &c1);
    sincosf((float)(pos0 + 1) * th, &sz, &cz);
    C1[nf] = c1; S1[nf] = s1; CZ[nf] = cz; SZ[nf] = sz;
  }
  __syncthreads();   // staging visible (own-wave vmcnt drained at barrier)

#pragma unroll
  for (int z = 0; z < 3; ++z) {
    // ---- compute: wave -> 16m x 64n (4 n-frag chains) ----
    f32x4 acc[4];
#pragma unroll
    for (int nf = 0; nf < 4; ++nf) acc[nf] = (f32x4){0.f, 0.f, 0.f, 0.f};
#pragma unroll
    for (int ks = 0; ks < 16; ++ks) {
      const int off = (((ks * 4) + g) ^ (r & 7)) << 3;
#pragma unroll
      for (int nf = 0; nf < 4; ++nf) {
        bf16x8 bb = *(const bf16x8*)&Bl[(nf * 16 + r) * 512 + off];
        acc[nf] = __builtin_amdgcn_mfma_f32_16x16x32_bf16(aa[ks], bb, acc[nf], 0, 0, 0);
      }
    }
    __syncthreads();   // all waves done reading Bl

    // ---- issue staging of next W plane into Bl (drains at epilogue barrier) ----
    if (z < 2) {
#pragma unroll
      for (int i = 0; i < 8; ++i) {
        const int row = wave * 8 + i;
        stage_row(Wt + (size_t)(z + 1) * 262144 + (size_t)(nbase + row) * 512,
                  &Bl[row * 512], lane, row & 7);
      }
    }

    // ---- epilogue ----
    if (z == 2) {
      // V: T as [n 64][pos 128], 16-granule XOR swizzle
#pragma unroll
      for (int nf = 0; nf < 4; ++nf) {
        const int nl = nf * 16 + r;
#pragma unroll
        for (int i = 0; i < 4; ++i) {
          const int pos = wave * 16 + g * 4 + i;
          const int sg = (pos >> 3) ^ (nl & 7);
          Tc[nl * 128 + sg * 8 + (pos & 7)] = f2bf(acc[nf][i]);
        }
      }
      __syncthreads();
#pragma unroll
      for (int pass = 0; pass < 2; ++pass) {
        const int row = tid >> 3;                 // 0..63 (n_local)
        const int gg = pass * 8 + (tid & 7);      // 0..15 (pos granule)
        const int sg = gg ^ (row & 7);
        bf16x8 v = *(const bf16x8*)&Tc[row * 128 + sg * 8];
        *(bf16x8*)&Vt[((size_t)b * 512 + nbase + row) * 2048 + posb + gg * 8] = v;
      }
    } else {
      // Q/K: single-pass fill of BOTH cos & sin planes (one rotation chain)
#pragma unroll
      for (int nf = 0; nf < 4; ++nf) {
        const int nl = nf * 16 + r;
        float cc = CZ[nf], ss = SZ[nf];
        const float c1 = C1[nf], s1 = S1[nf];
#pragma unroll
        for (int i = 0; i < 4; ++i) {
          const int mrow = wave * 16 + g * 4 + i;
          const int sc = ((((nl >> 3) ^ (mrow & 7)) << 3) | (nl & 7));
          Tc[mrow * 64 + sc] = f2bf(acc[nf][i] * cc);
          Ts[mrow * 64 + sc] = f2bf(acc[nf][i] * ss);
          float nc = cc * c1 - ss * s1, ns = cc * s1 + ss * c1;
          cc = nc; ss = ns;
        }
      }
      __syncthreads();                      // fill done (also drains W staging)
      unsigned short* dc = (z == 0) ? Qc : Kc;
      unsigned short* dsn = (z == 0) ? Qs : Ks;
#pragma unroll
      for (int pass = 0; pass < 2; ++pass) {
        const int row = pass * 64 + (tid >> 3);   // 0..127 (m_local)
        const int lg = tid & 7;
        const int sc8 = (lg ^ (row & 7)) << 3;
        bf16x8 vc = *(const bf16x8*)&Tc[row * 64 + sc8];
        bf16x8 vs = *(const bf16x8*)&Ts[row * 64 + sc8];
        const size_t o = (size_t)(mbase + row) * 512 + nbase + lg * 8;
        *(bf16x8*)&dc[o] = vc;
        *(bf16x8*)&dsn[o] = vs;
      }
    }
    __syncthreads();                        // T reads + staging complete before next z
  }
}

// ---------------- Stage 2: retention, QBLK=32 via q-group waves, m-tile 32 ----------
// (verbatim r18/r23 — proven) Output pack (verified): im | re<<16.
__global__ __launch_bounds__(256, 1) void ret_kernel(
    const unsigned short* __restrict__ Qc, const unsigned short* __restrict__ Qs,
    const unsigned short* __restrict__ Kc, const unsigned short* __restrict__ Ks,
    const unsigned short* __restrict__ Vt, uint32_t* __restrict__ out)
{
  __shared__ unsigned short Klds[64 * 512];   // rows 0-31: Kc, 32-63: Ks (swz granules)
  __shared__ unsigned short Prl[2][16 * 40];
  __shared__ unsigned short Pil[2][16 * 40];

  const int bid = blockIdx.x;
  const int sid = ((bid & 7) << 5) + (bid >> 3);  // XCD chunk swizzle (bijective, 256=8*32)
  const int b = sid >> 6;
  const int qblk = 63 - (sid & 63);               // heavy-first
  const int q0 = qblk * 32;
  const int tid = threadIdx.x;
  const int wave = tid >> 6;
  const int lane = tid & 63;
  const int r = lane & 15;
  const int g = lane >> 4;
  const int mf = wave & 1;
  const int wq = wave >> 1;
  const int sw = r & 7;

  bf16x8 qa[16], qb[16];
  {
    const unsigned short* qcr = Qc + ((size_t)b * 2048 + q0 + wq * 16 + r) * 512 + g * 8;
    const unsigned short* qsr = Qs + ((size_t)b * 2048 + q0 + wq * 16 + r) * 512 + g * 8;
#pragma unroll
    for (int ks = 0; ks < 16; ++ks) {
      qa[ks] = *(const bf16x8*)(qcr + ks * 32);
      qb[ks] = *(const bf16x8*)(qsr + ks * 32);
    }
  }
#pragma unroll
  for (int ks = 0; ks < 16; ++ks)
    asm volatile("" : "+v"(qa[ks]), "+v"(qb[ks]));   // pin: forbid remat from global

  const int ntiles = ((q0 + 31) >> 5) + 1;
  const int t0 = (q0 >= 256) ? ((q0 - 256) >> 5) : 0;   // decay band start (32-grain)

  {
    const size_t kbase = ((size_t)b * 2048 + (t0 << 5)) * 512;
#pragma unroll
    for (int i = 0; i < 16; ++i) {
      const int rid = wave * 16 + i;
      const int row = rid & 31;
      const unsigned short* src = ((rid < 32) ? Kc : Ks) + kbase + (size_t)row * 512;
      stage_row(src, &Klds[(size_t)rid * 512], lane, rid & 7);
    }
  }
  __syncthreads();

  f32x4 outre[2][8], outim[2][8];
#pragma unroll
  for (int qg = 0; qg < 2; ++qg)
#pragma unroll
    for (int c = 0; c < 8; ++c) {
      outre[qg][c] = (f32x4){0.f, 0.f, 0.f, 0.f};
      outim[qg][c] = (f32x4){0.f, 0.f, 0.f, 0.f};
    }

  for (int t = t0; t < ntiles; ++t) {
    const int m0 = t << 5;
    f32x4 acc_cc = {0.f, 0.f, 0.f, 0.f};
    f32x4 acc_ss = {0.f, 0.f, 0.f, 0.f};
    f32x4 ai1 = {0.f, 0.f, 0.f, 0.f};
    f32x4 ai2 = {0.f, 0.f, 0.f, 0.f};
    const unsigned short* krow_c = &Klds[(mf * 16 + r) * 512];
    const unsigned short* krow_s = krow_c + 32 * 512;
#pragma unroll
    for (int ks = 0; ks < 16; ++ks) {
      const int off = (((ks * 4) + g) ^ sw) << 3;
      bf16x8 ka = *(const bf16x8*)(krow_c + off);
      bf16x8 kb = *(const bf16x8*)(krow_s + off);
      acc_cc = __builtin_amdgcn_mfma_f32_16x16x32_bf16(ka, qa[ks], acc_cc, 0, 0, 0);
      acc_ss = __builtin_amdgcn_mfma_f32_16x16x32_bf16(kb, qb[ks], acc_ss, 0, 0, 0);
      ai1    = __builtin_amdgcn_mfma_f32_16x16x32_bf16(ka, qb[ks], ai1, 0, 0, 0);
      ai2    = __builtin_amdgcn_mfma_f32_16x16x32_bf16(kb, qa[ks], ai2, 0, 0, 0);
    }
    {
      const int qrow = q0 + wq * 16 + r;
      const int mg = m0 + mf * 16 + g * 4;
      ushort4 pkre, pkim;
#pragma unroll
      for (int rg = 0; rg < 4; ++rg) {
        int d = qrow - (mg + rg);
        float wdec = (d >= 0) ? exp2f((float)d * LOG2G) : 0.0f;
        ((unsigned short*)&pkre)[rg] = f2bf((acc_cc[rg] + acc_ss[rg]) * wdec);
        ((unsigned short*)&pkim)[rg] = f2bf((ai1[rg] - ai2[rg]) * wdec);
      }
      *(ushort4*)&Prl[wq][r * 40 + mf * 16 + g * 4] = pkre;
      *(ushort4*)&Pil[wq][r * 40 + mf * 16 + g * 4] = pkim;
    }
    __syncthreads();

    const unsigned short* vtp =
        Vt + ((size_t)b * 512 + wave * 128 + r) * 2048 + m0 + g * 8;
    bf16x8 vv[8];
#pragma unroll
    for (int c = 0; c < 8; ++c)
      vv[c] = *(const bf16x8*)(vtp + (size_t)c * 16 * 2048);

    if (t + 1 < ntiles) {
      const size_t kbase = ((size_t)b * 2048 + m0 + 32) * 512;
#pragma unroll
      for (int i = 0; i < 16; ++i) {
        const int rid = wave * 16 + i;
        const int row = rid & 31;
        const unsigned short* src = ((rid < 32) ? Kc : Ks) + kbase + (size_t)row * 512;
        stage_row(src, &Klds[(size_t)rid * 512], lane, rid & 7);
      }
    }

#pragma unroll
    for (int qg = 0; qg < 2; ++qg) {
      bf16x8 pr = *(const bf16x8*)&Prl[qg][r * 40 + g * 8];
      bf16x8 pi = *(const bf16x8*)&Pil[qg][r * 40 + g * 8];
#pragma unroll
      for (int c = 0; c < 8; ++c) {
        outre[qg][c] = __builtin_amdgcn_mfma_f32_16x16x32_bf16(pr, vv[c], outre[qg][c], 0, 0, 0);
        outim[qg][c] = __builtin_amdgcn_mfma_f32_16x16x32_bf16(pi, vv[c], outim[qg][c], 0, 0, 0);
      }
    }
    __syncthreads();
  }

#pragma unroll
  for (int qg = 0; qg < 2; ++qg)
#pragma unroll
    for (int c = 0; c < 8; ++c)
#pragma unroll
      for (int rg = 0; rg < 4; ++rg) {
        const int q = q0 + qg * 16 + g * 4 + rg;
        const int h = wave * 128 + c * 16 + r;
        const size_t o = ((size_t)b * 2048 + q) * 512 + h;
        out[o] = (uint32_t)f2bf(outim[qg][c][rg]) | ((uint32_t)f2bf(outre[qg][c][rg]) << 16);
      }
}

extern "C" void kernel_launch(void* const* d_in, const int* in_sizes, int n_in,
                              void* d_out, int out_size, void* d_ws, size_t ws_size,
                              hipStream_t stream) {
  (void)in_sizes; (void)n_in; (void)out_size; (void)ws_size;
  const float* x     = (const float*)d_in[0];
  const float* wq    = (const float*)d_in[1];
  const float* wk    = (const float*)d_in[2];
  const float* wv    = (const float*)d_in[3];
  const float* theta = (const float*)d_in[4];

  const size_t NEL = (size_t)4 * 2048 * 512;   // elements per bf16 matrix
  unsigned short* Qc = (unsigned short*)d_ws;
  unsigned short* Qs = Qc + NEL;
  unsigned short* Kc = Qs + NEL;
  unsigned short* Ks = Kc + NEL;
  unsigned short* Vt = Ks + NEL;               // [B][H][S]
  // transient buffers in d_out (fully overwritten by ret_kernel afterwards)
  unsigned short* Wt = (unsigned short*)d_out;             // 1.5 MB
  unsigned short* xb = (unsigned short*)d_out + 2097152;   // 8.4 MB @ 4MB offset

  prep_kernel<<<192, 256, 0, stream>>>(wq, wk, wv, Wt);
  xconv_kernel<<<2048, 256, 0, stream>>>(x, xb);
  dim3 gp(8, 64);
  proj_kernel<<<gp, 512, 0, stream>>>(xb, Wt, theta, Qc, Qs, Kc, Ks, Vt);
  ret_kernel<<<256, 256, 0, stream>>>(Qc, Qs, Kc, Ks, Vt, (uint32_t*)d_out);
}